// Round 11
// baseline (118.924 us; speedup 1.0000x reference)
//
#include <hip/hip_runtime.h>

typedef __attribute__((ext_vector_type(8))) short short8;
typedef __attribute__((ext_vector_type(4))) float f32x4;

#define ROWS 16384   // B*N
#define DIM 64
#define NCODES 8192
#define MARGIN 0.008f
#define KT_FB 256
#define CTS_PER_BLOCK 32   // 512 codes per y-block
#define CCH 2              // cts per LDS chunk (8 KB per buffer)

// ws layout (bytes)
#define WS_BEST   0            // 16384 * 8
#define WS_COUNTS 131072       // 8192 * 4
#define WS_ENH    163840       // 8192 * 4
#define WS_ESWZ   196608       // 8192*64*2 terms * 2B = 2097152
#define WS_NEED   2293760

__device__ __forceinline__ unsigned long long pack_score(float s, int idx) {
  unsigned u = __float_as_uint(s);
  u ^= (unsigned)((int)u >> 31) | 0x80000000u;
  return ((unsigned long long)u << 32) | (unsigned)(0xFFFF - idx);
}
__device__ __forceinline__ unsigned short bf16hi(float f) {
  unsigned u = __float_as_uint(f);
  return (unsigned short)((u + 0x7FFFu + ((u >> 16) & 1u)) >> 16);
}

__global__ void vq_enorm(const float* __restrict__ embed, float* __restrict__ enh) {
  int k = blockIdx.x * 256 + threadIdx.x;
  const float4* e4 = (const float4*)(embed + (size_t)k * DIM);
  float a = 0.f, b = 0.f, c = 0.f, d = 0.f;
#pragma unroll
  for (int i = 0; i < DIM / 4; ++i) {
    float4 v = e4[i];
    a = fmaf(v.x, v.x, a); b = fmaf(v.y, v.y, b);
    c = fmaf(v.z, v.z, c); d = fmaf(v.w, v.w, d);
  }
  enh[k] = 0.5f * ((a + b) + (c + d));
}

// Pre-swizzle embed into MFMA B-fragment order, split hi/lo bf16.
// frag index = ct*4 + kc*2 + term (term 0=hi, 1=lo); element l*16B within frag.
__global__ void vq_prep_e(const float* __restrict__ embed, short* __restrict__ eswz) {
  int u = blockIdx.x * 256 + threadIdx.x;  // 65536 = 512ct * 2kc * 64l
  int l = u & 63, kc = (u >> 6) & 1, ct = u >> 7;
  int code = ct * 16 + (l & 15);
  int kb = kc * 32 + (l >> 4) * 8;
  const float* er = embed + (size_t)code * DIM + kb;
  short8 h8, l8;
#pragma unroll
  for (int j = 0; j < 8; ++j) {
    float v = er[j];
    unsigned short h = bf16hi(v);
    float r = v - __uint_as_float((unsigned)h << 16);
    h8[j] = (short)h;
    l8[j] = (short)bf16hi(r);
  }
  short8* dst = (short8*)eswz;
  size_t frag = (size_t)ct * 4 + kc * 2;
  dst[(frag + 0) * 64 + l] = h8;
  dst[(frag + 1) * 64 + l] = l8;
}

// Screen, r11 structure: wave = 16 rows x 512 codes (1 slot). Working set
// ~55 VGPR -> fits the <=64-reg tier -> __launch_bounds__(256,8) = 8 waves/SIMD
// (r5-r10 all sat at ~95us because 32-row waves need ~110 regs = 4-wave tier;
// TLP, not ILP/prefetch, is what hides the latency+drain stalls).
// B-fragments LDS-staged per block (4 waves share; keeps L2 B-traffic at
// ~18 TB/s vs 70 TB/s unstaged), 2-ct double buffer (16 KB -> 8 blocks/CU).
// Single 6-deep MFMA chain per ct (acc = 4 regs), -||e||^2/2 in acc init.
// Float top-1 compare, margin-gated exact fp32 rescore, packed u64 atomicMax
// (bit-exact vs numpy argmax).
__global__ __launch_bounds__(256, 8) void vq_screen(
    const float* __restrict__ x, const float* __restrict__ embed,
    const short* __restrict__ eswz, const float* __restrict__ enh,
    unsigned long long* __restrict__ best) {
  const int t = threadIdx.x;
  const int l = t & 63, wid = t >> 6;
  const int cl = l & 15, grp = l >> 4;
  const int row0 = blockIdx.x * 64 + wid * 16;
  const int ct0 = blockIdx.y * CTS_PER_BLOCK;

  __shared__ short8 bstage[2][CCH * 4 * 64];  // 2 x 8 KB

  const char* gbase = (const char*)eswz + (size_t)ct0 * 4 * 1024;

  // stage chunk 0 (latency overlaps A-frag setup)
  {
    char* lb = (char*)&bstage[0][0];
#pragma unroll
    for (int i = 0; i < CCH; ++i) {
      const int e = i * 256 + t;
      __builtin_amdgcn_global_load_lds(
          (const __attribute__((address_space(1))) void*)(gbase + (size_t)e * 16),
          (__attribute__((address_space(3))) void*)(lb + e * 16), 16, 0, 0);
    }
  }

  // A fragments: 16 x rows -> hi/lo bf16, in-register (16 VGPRs total).
  short8 ahi[2], alo[2];
  {
    const float4* xr4 = (const float4*)(x + (size_t)(row0 + cl) * DIM);
#pragma unroll
    for (int kc = 0; kc < 2; ++kc) {
      const int q = kc * 8 + grp * 2;  // float4 index of kb = kc*32+grp*8
      float4 v0 = xr4[q], v1 = xr4[q + 1];
      float vv[8] = {v0.x, v0.y, v0.z, v0.w, v1.x, v1.y, v1.z, v1.w};
#pragma unroll
      for (int j = 0; j < 8; ++j) {
        unsigned short h = bf16hi(vv[j]);
        float r = vv[j] - __uint_as_float((unsigned)h << 16);
        ahi[kc][j] = (short)h;
        alo[kc][j] = (short)bf16hi(r);
      }
    }
  }

  float bsc[4];
  int bidx[4];
#pragma unroll
  for (int j = 0; j < 4; ++j) { bsc[j] = -3.4e38f; bidx[j] = 0; }

  __syncthreads();  // chunk 0 staged

  for (int ch = 0; ch < CTS_PER_BLOCK / CCH; ++ch) {
    const int cur = ch & 1;
    // prefetch next chunk into the other buffer (drained at end-of-chunk barrier)
    if (ch + 1 < CTS_PER_BLOCK / CCH) {
      const char* gb = gbase + (size_t)(ch + 1) * CCH * 4 * 1024;
      char* lb = (char*)&bstage[cur ^ 1][0];
#pragma unroll
      for (int i = 0; i < CCH; ++i) {
        const int e = i * 256 + t;
        __builtin_amdgcn_global_load_lds(
            (const __attribute__((address_space(1))) void*)(gb + (size_t)e * 16),
            (__attribute__((address_space(3))) void*)(lb + e * 16), 16, 0, 0);
      }
    }

    const short8* bs = &bstage[cur][0];
#pragma unroll
    for (int cil = 0; cil < CCH; ++cil) {
      const int ci = ch * CCH + cil;  // local ct
      const float eh = enh[(ct0 + ci) * 16 + cl];
      short8 h0 = bs[(cil * 4 + 0) * 64 + l], l0 = bs[(cil * 4 + 1) * 64 + l];
      short8 h1 = bs[(cil * 4 + 2) * 64 + l], l1 = bs[(cil * 4 + 3) * 64 + l];

      f32x4 acc = {-eh, -eh, -eh, -eh};
      acc = __builtin_amdgcn_mfma_f32_16x16x32_bf16(ahi[0], h0, acc, 0, 0, 0);
      acc = __builtin_amdgcn_mfma_f32_16x16x32_bf16(alo[0], h0, acc, 0, 0, 0);
      acc = __builtin_amdgcn_mfma_f32_16x16x32_bf16(ahi[0], l0, acc, 0, 0, 0);
      acc = __builtin_amdgcn_mfma_f32_16x16x32_bf16(ahi[1], h1, acc, 0, 0, 0);
      acc = __builtin_amdgcn_mfma_f32_16x16x32_bf16(alo[1], h1, acc, 0, 0, 0);
      acc = __builtin_amdgcn_mfma_f32_16x16x32_bf16(ahi[1], l1, acc, 0, 0, 0);

      const int code = (ct0 + ci) * 16 + cl;
#pragma unroll
      for (int j = 0; j < 4; ++j) {
        if (acc[j] > bsc[j]) { bsc[j] = acc[j]; bidx[j] = code; }
      }
    }
    __syncthreads();  // done reading bstage[cur]; prefetch drained
  }

  // Row max over the 16 lanes (cl) of each grp group; flag lane-bests within margin.
  unsigned fmask = 0;
#pragma unroll
  for (int j = 0; j < 4; ++j) {
    float m = bsc[j];
    m = fmaxf(m, __shfl_xor(m, 1));
    m = fmaxf(m, __shfl_xor(m, 2));
    m = fmaxf(m, __shfl_xor(m, 4));
    m = fmaxf(m, __shfl_xor(m, 8));
    if (bsc[j] >= m - MARGIN) fmask |= 1u << j;
  }

  // Exact fp32 rescore of flagged candidates (typically 1/lane), lane-compacted.
  float exact[4];
#pragma unroll
  for (int j = 0; j < 4; ++j) exact[j] = -3.4e38f;

  while (__any((int)(fmask != 0))) {
    const bool act = fmask != 0;
    const int sel = act ? __ffs(fmask) - 1 : 0;
    int code = 0;
#pragma unroll
    for (int j = 0; j < 4; ++j) code = (sel == j) ? bidx[j] : code;
    int row = act ? (row0 + grp * 4 + sel) : row0;
    if (!act) code = 0;
    const float4* xr = (const float4*)(x + (size_t)row * DIM);
    const float4* er = (const float4*)(embed + (size_t)code * DIM);
    float a0 = 0, a1 = 0, a2 = 0, a3 = 0, n0 = 0, n1 = 0, n2 = 0, n3 = 0;
#pragma unroll
    for (int i = 0; i < 16; ++i) {
      float4 xv = xr[i], ev = er[i];
      a0 = fmaf(xv.x, ev.x, a0); a1 = fmaf(xv.y, ev.y, a1);
      a2 = fmaf(xv.z, ev.z, a2); a3 = fmaf(xv.w, ev.w, a3);
      n0 = fmaf(ev.x, ev.x, n0); n1 = fmaf(ev.y, ev.y, n1);
      n2 = fmaf(ev.z, ev.z, n2); n3 = fmaf(ev.w, ev.w, n3);
    }
    float ex = ((a0 + a1) + (a2 + a3)) - 0.5f * ((n0 + n1) + (n2 + n3));
#pragma unroll
    for (int j = 0; j < 4; ++j)
      exact[j] = (act && sel == j) ? ex : exact[j];
    fmask = act ? (fmask & (fmask - 1)) : 0u;
  }

  // (exact score, lowest-idx) reduce across the 16-lane group; atomicMax combine.
#pragma unroll
  for (int j = 0; j < 4; ++j) {
    unsigned long long pk = pack_score(exact[j], bidx[j]);
    unsigned long long o;
    o = __shfl_xor(pk, 1); pk = pk > o ? pk : o;
    o = __shfl_xor(pk, 2); pk = pk > o ? pk : o;
    o = __shfl_xor(pk, 4); pk = pk > o ? pk : o;
    o = __shfl_xor(pk, 8); pk = pk > o ? pk : o;
    if (cl == 0) atomicMax(&best[row0 + grp * 4 + j], pk);
  }
}

// Fallback (proven round-1 path) if ws is too small for the MFMA screen.
__global__ __launch_bounds__(256, 2) void vq_score_fb(
    const float* __restrict__ x, const float* __restrict__ embed,
    const float* __restrict__ enh, unsigned long long* __restrict__ best) {
  const int row = blockIdx.x * 256 + threadIdx.x;
  const int c0 = blockIdx.y * KT_FB;
  float4 xa[16];
  const float4* xg = (const float4*)(x + (size_t)row * DIM);
#pragma unroll
  for (int i = 0; i < 16; ++i) xa[i] = xg[i];
  float bs = -3.4e38f;
  int bc = 0;
#pragma unroll 2
  for (int c = c0; c < c0 + KT_FB; ++c) {
    const float4* e4 = (const float4*)(embed + (size_t)c * DIM);
    float a0 = 0.f, a1 = 0.f, a2 = 0.f, a3 = 0.f;
#pragma unroll
    for (int i = 0; i < 16; ++i) {
      float4 ev = e4[i];
      a0 = fmaf(xa[i].x, ev.x, a0); a1 = fmaf(xa[i].y, ev.y, a1);
      a2 = fmaf(xa[i].z, ev.z, a2); a3 = fmaf(xa[i].w, ev.w, a3);
    }
    float s = ((a0 + a1) + (a2 + a3)) - enh[c];
    if (s > bs) { bs = s; bc = c; }
  }
  atomicMax(&best[row], pack_score(bs, bc));
}

__global__ void vq_finalize(const unsigned long long* __restrict__ best,
                            const float* __restrict__ embed,
                            const float* __restrict__ node_mask,
                            float* __restrict__ quant,
                            float* __restrict__ out_idx,
                            float* __restrict__ counts) {
  int gid = blockIdx.x * 256 + threadIdx.x;
  int row = gid >> 6, d = gid & 63;
  unsigned long long p = best[row];
  int idx = 0xFFFF - (int)(p & 0xFFFFull);
  quant[gid] = embed[(size_t)idx * DIM + d];
  if (d == 0) {
    out_idx[row] = (float)idx;
    atomicAdd(&counts[idx], node_mask[row]);
  }
}

__global__ void vq_perplexity(const float* __restrict__ counts, float* __restrict__ out) {
  int tid = threadIdx.x;
  float acc = 0.f;
  for (int k = tid; k < NCODES; k += 256) {
    float p = counts[k] * (1.0f / (float)ROWS);
    acc += p * logf(p + 1e-10f);
  }
#pragma unroll
  for (int off = 32; off > 0; off >>= 1) acc += __shfl_down(acc, off);
  __shared__ float red[4];
  if ((tid & 63) == 0) red[tid >> 6] = acc;
  __syncthreads();
  if (tid == 0) out[0] = expf(-((red[0] + red[1]) + (red[2] + red[3])));
}

extern "C" void kernel_launch(void* const* d_in, const int* in_sizes, int n_in,
                              void* d_out, int out_size, void* d_ws, size_t ws_size,
                              hipStream_t stream) {
  const float* x = (const float*)d_in[0];
  const float* node_mask = (const float*)d_in[1];
  const float* embed = (const float*)d_in[2];

  float* out = (float*)d_out;
  float* quant = out;
  float* out_idx = out + (size_t)ROWS * DIM;
  float* out_ppl = out_idx + ROWS;

  unsigned long long* best = (unsigned long long*)((char*)d_ws + WS_BEST);
  float* counts = (float*)((char*)d_ws + WS_COUNTS);
  float* enh = (float*)((char*)d_ws + WS_ENH);
  short* eswz = (short*)((char*)d_ws + WS_ESWZ);

  hipMemsetAsync(d_ws, 0, WS_ENH, stream);  // best + counts
  vq_enorm<<<NCODES / 256, 256, 0, stream>>>(embed, enh);
  if (ws_size >= WS_NEED) {
    vq_prep_e<<<256, 256, 0, stream>>>(embed, eswz);
    vq_screen<<<dim3(ROWS / 64, NCODES / (CTS_PER_BLOCK * 16)), 256, 0, stream>>>(
        x, embed, eswz, enh, best);
  } else {
    vq_score_fb<<<dim3(ROWS / 256, NCODES / KT_FB), 256, 0, stream>>>(x, embed, enh, best);
  }
  vq_finalize<<<ROWS * DIM / 256, 256, 0, stream>>>(best, embed, node_mask, quant, out_idx, counts);
  vq_perplexity<<<1, 256, 0, stream>>>(counts, out_ppl);
}